// Round 3
// baseline (380.149 us; speedup 1.0000x reference)
//
#include <hip/hip_runtime.h>
#include <hip/hip_bf16.h>
#include <stdint.h>

#define M_DIM 1024
#define K_DIM 4096
#define N_DIM 11008
#define NPACK 1376  // N/8
#define NGROUPS 32

typedef __attribute__((ext_vector_type(4))) float f32x4;
typedef __attribute__((ext_vector_type(8))) _Float16 f16x8;

// pack two f32 -> two fp16 in one uint (v_cvt_f16_f32 x2 + pack)
static __device__ __forceinline__ unsigned int pack2h(float a, float b) {
  _Float16 ha = (_Float16)a, hb = (_Float16)b;
  unsigned short ua = __builtin_bit_cast(unsigned short, ha);
  unsigned short ub = __builtin_bit_cast(unsigned short, hb);
  return (unsigned int)ua | ((unsigned int)ub << 16);
}

__global__ __launch_bounds__(256)
void awq_gemm(const float* __restrict__ X,
              const int* __restrict__ QW,
              const int* __restrict__ QZ,
              const float* __restrict__ S,
              const float* __restrict__ BIAS,
              float* __restrict__ OUT)
{
  __shared__ unsigned short Alds[128 * 64];  // [m][k] fp16, 16 KiB
  __shared__ unsigned short Blds[128 * 64];  // [n][k] (B^T) fp16, 16 KiB

  const int tid  = threadIdx.x;
  const int lane = tid & 63;
  const int wid  = tid >> 6;
  const int wr   = wid >> 1;   // wave row (2)
  const int wc   = wid & 1;    // wave col (2)
  const int l15  = lane & 15;
  const int l4   = lane >> 4;

  const int bn   = blockIdx.x;      // 0..85
  const int bm   = blockIdx.y;      // 0..7
  const int row0 = bm * 128;
  const int n0   = bn * 128;
  const int p0   = n0 >> 3;         // first pack of this N-tile (16 packs)

  // dequant mapping: thread = 1 pack x 4 consecutive k
  const int dq_p = tid & 15;
  const int dq_k = (tid >> 4) << 2;

  f32x4 acc[4][4];
  #pragma unroll
  for (int i = 0; i < 4; ++i)
    #pragma unroll
    for (int j = 0; j < 4; ++j)
      acc[i][j] = (f32x4){0.f, 0.f, 0.f, 0.f};

  for (int k0 = 0; k0 < K_DIM; k0 += 64) {
    // ---- global loads to REGISTERS: A tile (fp32 x -> fp16) ----
    uint4 av[4];
    #pragma unroll
    for (int i = 0; i < 4; ++i) {
      const int g = i * 256 + tid;               // 8-elem granule index, 0..1023
      const float* src = X + (size_t)(row0 + (g >> 3)) * K_DIM + k0 + ((g & 7) << 3);
      const float4 v0 = *(const float4*)(src);
      const float4 v1 = *(const float4*)(src + 4);
      av[i].x = pack2h(v0.x, v0.y);
      av[i].y = pack2h(v0.z, v0.w);
      av[i].z = pack2h(v1.x, v1.y);
      av[i].w = pack2h(v1.z, v1.w);
    }

    const int grp = k0 >> 7;  // BK=64 divides GROUP=128 => uniform per tile
    const unsigned int qz = (unsigned int)QZ[grp * NPACK + p0 + dq_p];
    const float4 sv0 = *(const float4*)(S + (size_t)grp * N_DIM + n0 + dq_p * 8);
    const float4 sv1 = *(const float4*)(S + (size_t)grp * N_DIM + n0 + dq_p * 8 + 4);
    const float svf[8] = {sv0.x, sv0.y, sv0.z, sv0.w, sv1.x, sv1.y, sv1.z, sv1.w};

    unsigned int qw[4];
    #pragma unroll
    for (int i = 0; i < 4; ++i)
      qw[i] = (unsigned int)QW[(size_t)(k0 + dq_k + i) * NPACK + p0 + dq_p];

    // ---- dequant 8 n-columns x 4 k in registers (fp32 math, fp16 round) ----
    uint2 wb[8];
    #pragma unroll
    for (int j = 0; j < 8; ++j) {
      // AWQ reverse order [0,4,1,5,2,6,3,7] -> nibble shifts
      const int SH[8] = {0, 16, 4, 20, 8, 24, 12, 28};
      const int sh = SH[j];
      const float sj  = svf[j];
      const float nzs = -(float)((qz >> sh) & 15u) * sj;

      const float f0 = fmaf((float)((qw[0] >> sh) & 15u), sj, nzs);
      const float f1 = fmaf((float)((qw[1] >> sh) & 15u), sj, nzs);
      const float f2 = fmaf((float)((qw[2] >> sh) & 15u), sj, nzs);
      const float f3 = fmaf((float)((qw[3] >> sh) & 15u), sj, nzs);

      wb[j].x = pack2h(f0, f1);
      wb[j].y = pack2h(f2, f3);
    }

    __syncthreads();  // previous tile's MFMA reads done before LDS overwrite

    // ---- commit to LDS ----
    #pragma unroll
    for (int i = 0; i < 4; ++i) {
      const int g = i * 256 + tid;
      *(uint4*)&Alds[g * 8] = av[i];            // A[m][k], row stride 64
    }
    #pragma unroll
    for (int j = 0; j < 8; ++j)
      *(uint2*)&Blds[(dq_p * 8 + j) * 64 + dq_k] = wb[j];  // B^T[n][k]

    __syncthreads();  // LDS visible to all waves

    // ---- MFMA: 2 k-halves x 4x4 fragments (fp16 inputs, fp32 accum) ----
    #pragma unroll
    for (int kk = 0; kk < 2; ++kk) {
      f16x8 af[4], bfr[4];
      #pragma unroll
      for (int m = 0; m < 4; ++m)
        af[m] = *(const f16x8*)&Alds[(wr * 64 + m * 16 + l15) * 64 + kk * 32 + l4 * 8];
      #pragma unroll
      for (int n = 0; n < 4; ++n)
        bfr[n] = *(const f16x8*)&Blds[(wc * 64 + n * 16 + l15) * 64 + kk * 32 + l4 * 8];
      #pragma unroll
      for (int m = 0; m < 4; ++m)
        #pragma unroll
        for (int n = 0; n < 4; ++n)
          acc[m][n] = __builtin_amdgcn_mfma_f32_16x16x32_f16(af[m], bfr[n], acc[m][n], 0, 0, 0);
    }
  }

  // ---- epilogue: + bias, store fp32 ----
  // C/D layout (verified m89, dtype-independent): col = lane&15, row = (lane>>4)*4 + reg
  #pragma unroll
  for (int n = 0; n < 4; ++n) {
    const int col = n0 + wc * 64 + n * 16 + l15;
    const float bz = BIAS[col];
    #pragma unroll
    for (int m = 0; m < 4; ++m) {
      const int rbase = row0 + wr * 64 + m * 16 + l4 * 4;
      #pragma unroll
      for (int r = 0; r < 4; ++r) {
        OUT[(size_t)(rbase + r) * N_DIM + col] = acc[m][n][r] + bz;
      }
    }
  }
}

extern "C" void kernel_launch(void* const* d_in, const int* in_sizes, int n_in,
                              void* d_out, int out_size, void* d_ws, size_t ws_size,
                              hipStream_t stream) {
  // identify inputs by element count (all distinct) — robust to ordering
  const float* x = nullptr; const int* qw = nullptr; const int* qz = nullptr;
  const float* s = nullptr; const float* b = nullptr;
  for (int i = 0; i < n_in; ++i) {
    switch (in_sizes[i]) {
      case M_DIM * K_DIM:      x  = (const float*)d_in[i]; break;  // 4194304
      case K_DIM * NPACK:      qw = (const int*)d_in[i];   break;  // 5636096
      case NGROUPS * NPACK:    qz = (const int*)d_in[i];   break;  // 44032
      case NGROUPS * N_DIM:    s  = (const float*)d_in[i]; break;  // 352256
      case N_DIM:              b  = (const float*)d_in[i]; break;  // 11008
    }
  }
  float* out = (float*)d_out;

  dim3 grid(N_DIM / 128, M_DIM / 128);  // 86 x 8
  awq_gemm<<<grid, dim3(256), 0, stream>>>(x, qw, qz, s, b, out);
}

// Round 4
// 187.494 us; speedup vs baseline: 2.0275x; 2.0275x over previous
//
#include <hip/hip_runtime.h>
#include <stdint.h>

#define M_DIM 1024
#define K_DIM 4096
#define N_DIM 11008
#define NPACK 1376
#define NGROUPS 32

typedef __attribute__((ext_vector_type(4))) float f32x4;
typedef __attribute__((ext_vector_type(8))) _Float16 f16x8;
typedef __attribute__((ext_vector_type(2))) _Float16 h2;

static __device__ __forceinline__ unsigned int swz(unsigned int r) {
  return (r ^ (r >> 3)) & 7u;  // 16B-granule XOR swizzle within 128B row
}

// prepass: x fp32 -> fp16 (exact: x was originally fp16)
__global__ __launch_bounds__(256)
void conv_x(const float* __restrict__ X, unsigned short* __restrict__ XH) {
  const size_t i = ((size_t)blockIdx.x * 256 + threadIdx.x) * 8;
  const float4 a = *(const float4*)(X + i);
  const float4 b = *(const float4*)(X + i + 4);
  uint4 o;
  o.x = __builtin_bit_cast(unsigned int, __builtin_amdgcn_cvt_pkrtz(a.x, a.y));
  o.y = __builtin_bit_cast(unsigned int, __builtin_amdgcn_cvt_pkrtz(a.z, a.w));
  o.z = __builtin_bit_cast(unsigned int, __builtin_amdgcn_cvt_pkrtz(b.x, b.y));
  o.w = __builtin_bit_cast(unsigned int, __builtin_amdgcn_cvt_pkrtz(b.z, b.w));
  *(uint4*)(XH + i) = o;
}

template <bool PRE>
__global__ __launch_bounds__(256)
void awq_gemm(const unsigned short* __restrict__ XH,  // fp16 x (PRE)
              const float* __restrict__ XF,           // fp32 x (!PRE)
              const int* __restrict__ QW,
              const int* __restrict__ QZ,
              const float* __restrict__ S,
              const float* __restrict__ BIAS,
              float* __restrict__ OUT)
{
  __shared__ unsigned short Alds[128 * 64];  // [m][k] fp16, swizzled granules
  __shared__ unsigned short Blds[128 * 64];  // [n][k] fp16, swizzled granules

  const int tid  = threadIdx.x;
  const int lane = tid & 63;
  const int wid  = tid >> 6;
  const int wr   = wid >> 1;
  const int wc   = wid & 1;
  const int l15  = lane & 15;
  const int l4   = lane >> 4;

  const int row0 = blockIdx.y * 128;
  const int n0   = blockIdx.x * 128;
  const int p0   = n0 >> 3;

  const int dq_p = tid & 15;
  const int dq_k = (tid >> 4) << 2;

  f32x4 acc[4][4];
  #pragma unroll
  for (int i = 0; i < 4; ++i)
    #pragma unroll
    for (int j = 0; j < 4; ++j)
      acc[i][j] = (f32x4){0.f, 0.f, 0.f, 0.f};

  const int SH[8] = {0, 16, 4, 20, 8, 24, 12, 28};  // 4*AWQ_REVERSE_ORDER[j]
  unsigned int zz[8];  // packed fp16 (1024+z, 1024+z)
  unsigned int ss[8];  // packed fp16 (s, s)

  // ---- prologue prefetch ----
  unsigned int qw[4];
  #pragma unroll
  for (int i = 0; i < 4; ++i)
    qw[i] = (unsigned int)QW[(size_t)(dq_k + i) * NPACK + p0 + dq_p];

  uint4 av[4];
  if (!PRE) {
    #pragma unroll
    for (int i = 0; i < 4; ++i) {
      const int g = i * 256 + tid;
      const float* src = XF + (size_t)(row0 + (g >> 3)) * K_DIM + ((g & 7) << 3);
      const float4 v0 = *(const float4*)src;
      const float4 v1 = *(const float4*)(src + 4);
      av[i].x = __builtin_bit_cast(unsigned int, __builtin_amdgcn_cvt_pkrtz(v0.x, v0.y));
      av[i].y = __builtin_bit_cast(unsigned int, __builtin_amdgcn_cvt_pkrtz(v0.z, v0.w));
      av[i].z = __builtin_bit_cast(unsigned int, __builtin_amdgcn_cvt_pkrtz(v1.x, v1.y));
      av[i].w = __builtin_bit_cast(unsigned int, __builtin_amdgcn_cvt_pkrtz(v1.z, v1.w));
    }
  }

  for (int k0 = 0; k0 < K_DIM; k0 += 64) {
    // ---- per-group (128) zero/scale prep, hoisted ----
    if ((k0 & 127) == 0) {
      const int grp = k0 >> 7;
      const unsigned int qzv = (unsigned int)QZ[grp * NPACK + p0 + dq_p];
      const float* sp = S + (size_t)grp * N_DIM + n0 + dq_p * 8;
      const float4 sv0 = *(const float4*)sp;
      const float4 sv1 = *(const float4*)(sp + 4);
      const float svf[8] = {sv0.x, sv0.y, sv0.z, sv0.w, sv1.x, sv1.y, sv1.z, sv1.w};
      #pragma unroll
      for (int j = 0; j < 8; ++j) {
        const unsigned int z = (qzv >> SH[j]) & 15u;
        zz[j] = z * 0x10001u + 0x64006400u;
        ss[j] = __builtin_bit_cast(unsigned int, __builtin_amdgcn_cvt_pkrtz(svf[j], svf[j]));
      }
    }

    // ---- dequant B in regs: packed fp16, exact (q-z) then one fp16 rounding ----
    uint2 wb[8];
    #pragma unroll
    for (int j = 0; j < 8; ++j) {
      const int sh = SH[j];
      const unsigned int q01 =
          ((qw[0] >> sh) & 15u) | (((qw[1] >> sh) & 15u) << 16) | 0x64006400u;
      const unsigned int q23 =
          ((qw[2] >> sh) & 15u) | (((qw[3] >> sh) & 15u) << 16) | 0x64006400u;
      const h2 w01 = (__builtin_bit_cast(h2, q01) - __builtin_bit_cast(h2, zz[j])) *
                     __builtin_bit_cast(h2, ss[j]);
      const h2 w23 = (__builtin_bit_cast(h2, q23) - __builtin_bit_cast(h2, zz[j])) *
                     __builtin_bit_cast(h2, ss[j]);
      wb[j].x = __builtin_bit_cast(unsigned int, w01);
      wb[j].y = __builtin_bit_cast(unsigned int, w23);
    }

    __syncthreads();  // previous tile's MFMA reads complete

    // ---- stage A ----
    if (PRE) {
      // linear LDS dest + inverse-swizzled global source (rule #21)
      #pragma unroll
      for (int i = 0; i < 4; ++i) {
        const int gb = i * 256 + wid * 64;  // wave-uniform granule base
        const int g  = gb + lane;
        const unsigned int r = g >> 3, c = g & 7;
        const unsigned short* gsrc =
            XH + (size_t)(row0 + r) * K_DIM + k0 + ((c ^ swz(r)) << 3);
        __builtin_amdgcn_global_load_lds(
            (const __attribute__((address_space(1))) void*)gsrc,
            (__attribute__((address_space(3))) void*)(&Alds[gb * 8]),
            16, 0, 0);
      }
    } else {
      #pragma unroll
      for (int i = 0; i < 4; ++i) {
        const int g = i * 256 + tid;
        const unsigned int r = g >> 3, c = g & 7;
        *(uint4*)((char*)Alds + r * 128 + ((c ^ swz(r)) << 4)) = av[i];
      }
    }

    // ---- write B (swizzled; 2-way max on banks) ----
    #pragma unroll
    for (int j = 0; j < 8; ++j) {
      const unsigned int nn = dq_p * 8 + j;
      *(uint2*)((char*)Blds + nn * 128 + ((dq_k * 2) ^ (swz(nn) << 4))) = wb[j];
    }

    __syncthreads();  // vmcnt+lgkmcnt drained by compiler before barrier

    // ---- prefetch next K-step's inputs (overlaps MFMA) ----
    if (k0 + 64 < K_DIM) {
      #pragma unroll
      for (int i = 0; i < 4; ++i)
        qw[i] = (unsigned int)QW[(size_t)(k0 + 64 + dq_k + i) * NPACK + p0 + dq_p];
      if (!PRE) {
        #pragma unroll
        for (int i = 0; i < 4; ++i) {
          const int g = i * 256 + tid;
          const float* src =
              XF + (size_t)(row0 + (g >> 3)) * K_DIM + (k0 + 64) + ((g & 7) << 3);
          const float4 v0 = *(const float4*)src;
          const float4 v1 = *(const float4*)(src + 4);
          av[i].x = __builtin_bit_cast(unsigned int, __builtin_amdgcn_cvt_pkrtz(v0.x, v0.y));
          av[i].y = __builtin_bit_cast(unsigned int, __builtin_amdgcn_cvt_pkrtz(v0.z, v0.w));
          av[i].z = __builtin_bit_cast(unsigned int, __builtin_amdgcn_cvt_pkrtz(v1.x, v1.y));
          av[i].w = __builtin_bit_cast(unsigned int, __builtin_amdgcn_cvt_pkrtz(v1.z, v1.w));
        }
      }
    }

    // ---- MFMA: 2 k-halves x 4x4 fragments ----
    #pragma unroll
    for (int kk = 0; kk < 2; ++kk) {
      f16x8 af[4], bfv[4];
      #pragma unroll
      for (int m = 0; m < 4; ++m) {
        const unsigned int r = wr * 64 + m * 16 + l15;
        af[m] = *(const f16x8*)((const char*)Alds + r * 128 +
                                (((unsigned)(kk * 4 + l4) ^ swz(r)) << 4));
      }
      #pragma unroll
      for (int n = 0; n < 4; ++n) {
        const unsigned int r = wc * 64 + n * 16 + l15;
        bfv[n] = *(const f16x8*)((const char*)Blds + r * 128 +
                                 (((unsigned)(kk * 4 + l4) ^ swz(r)) << 4));
      }
      #pragma unroll
      for (int m = 0; m < 4; ++m)
        #pragma unroll
        for (int n = 0; n < 4; ++n)
          acc[m][n] = __builtin_amdgcn_mfma_f32_16x16x32_f16(af[m], bfv[n], acc[m][n], 0, 0, 0);
    }
  }

  // ---- epilogue: + bias, store fp32 ----
  // C/D layout (m89, dtype-independent): col = lane&15, row = (lane>>4)*4 + reg
  #pragma unroll
  for (int n = 0; n < 4; ++n) {
    const int col = n0 + wc * 64 + n * 16 + l15;
    const float bz = BIAS[col];
    #pragma unroll
    for (int m = 0; m < 4; ++m) {
      const int rbase = row0 + wr * 64 + m * 16 + l4 * 4;
      #pragma unroll
      for (int r = 0; r < 4; ++r) {
        OUT[(size_t)(rbase + r) * N_DIM + col] = acc[m][n][r] + bz;
      }
    }
  }
}

extern "C" void kernel_launch(void* const* d_in, const int* in_sizes, int n_in,
                              void* d_out, int out_size, void* d_ws, size_t ws_size,
                              hipStream_t stream) {
  const float* x = nullptr; const int* qw = nullptr; const int* qz = nullptr;
  const float* s = nullptr; const float* b = nullptr;
  for (int i = 0; i < n_in; ++i) {
    switch (in_sizes[i]) {
      case M_DIM * K_DIM:   x  = (const float*)d_in[i]; break;
      case K_DIM * NPACK:   qw = (const int*)d_in[i];   break;
      case NGROUPS * NPACK: qz = (const int*)d_in[i];   break;
      case NGROUPS * N_DIM: s  = (const float*)d_in[i]; break;
      case N_DIM:           b  = (const float*)d_in[i]; break;
    }
  }
  float* out = (float*)d_out;

  dim3 grid(N_DIM / 128, M_DIM / 128);  // 86 x 8
  const size_t xh_bytes = (size_t)M_DIM * K_DIM * 2;
  if (ws_size >= xh_bytes) {
    unsigned short* xh = (unsigned short*)d_ws;
    conv_x<<<(M_DIM * K_DIM) / (256 * 8), 256, 0, stream>>>(x, xh);
    awq_gemm<true><<<grid, dim3(256), 0, stream>>>(xh, nullptr, qw, qz, s, b, out);
  } else {
    awq_gemm<false><<<grid, dim3(256), 0, stream>>>(nullptr, x, qw, qz, s, b, out);
  }
}

// Round 5
// 160.532 us; speedup vs baseline: 2.3681x; 1.1680x over previous
//
#include <hip/hip_runtime.h>
#include <stdint.h>

#define M_DIM 1024
#define K_DIM 4096
#define N_DIM 11008
#define NPACK 1376
#define NGROUPS 32

#define BM 256
#define BN 256
#define BK 64
#define NT (K_DIM / BK)     // 64
#define ATILE (BM * BK)     // 16384 elems = 32 KiB
#define BTILE (BN * BK)

typedef __attribute__((ext_vector_type(4))) float f32x4;
typedef __attribute__((ext_vector_type(8))) _Float16 f16x8;
typedef __attribute__((ext_vector_type(2))) _Float16 h2;

static __device__ __forceinline__ unsigned int swz(unsigned int r) {
  return (r ^ (r >> 3)) & 7u;  // 16B-granule XOR swizzle within 128B row
}

// prepass: x fp32 -> fp16 (exact: x was originally fp16)
__global__ __launch_bounds__(256)
void conv_x(const float* __restrict__ X, unsigned short* __restrict__ XH) {
  const size_t i = ((size_t)blockIdx.x * 256 + threadIdx.x) * 8;
  const float4 a = *(const float4*)(X + i);
  const float4 b = *(const float4*)(X + i + 4);
  uint4 o;
  o.x = __builtin_bit_cast(unsigned int, __builtin_amdgcn_cvt_pkrtz(a.x, a.y));
  o.y = __builtin_bit_cast(unsigned int, __builtin_amdgcn_cvt_pkrtz(a.z, a.w));
  o.z = __builtin_bit_cast(unsigned int, __builtin_amdgcn_cvt_pkrtz(b.x, b.y));
  o.w = __builtin_bit_cast(unsigned int, __builtin_amdgcn_cvt_pkrtz(b.z, b.w));
  *(uint4*)(XH + i) = o;
}

template <bool PRE>
__global__ __launch_bounds__(512, 2)
void awq_gemm(const unsigned short* __restrict__ XH,  // fp16 x (PRE)
              const float* __restrict__ XF,           // fp32 x (!PRE fallback)
              const int* __restrict__ QW,
              const int* __restrict__ QZ,
              const float* __restrict__ S,
              const float* __restrict__ BIAS,
              float* __restrict__ OUT)
{
  __shared__ unsigned short Alds[2][ATILE];  // [m][k] fp16, swizzled granules
  __shared__ unsigned short Blds[2][BTILE];  // [n][k] fp16, swizzled granules

  const int tid  = threadIdx.x;
  const int lane = tid & 63;
  const int wid  = tid >> 6;      // 0..7
  const int wr   = wid >> 2;      // 2 wave-rows (M)
  const int wc   = wid & 3;       // 4 wave-cols (N)
  const int l15  = lane & 15;
  const int l4   = lane >> 4;

  const int row0 = blockIdx.y * BM;
  const int n0   = blockIdx.x * BN;
  const int p0   = n0 >> 3;       // 32 packs per N-tile

  const int dq_p = tid & 31;          // pack within tile
  const int dq_k = (tid >> 5) << 2;   // 4 consecutive k

  f32x4 acc[8][4];
  #pragma unroll
  for (int i = 0; i < 8; ++i)
    #pragma unroll
    for (int j = 0; j < 4; ++j)
      acc[i][j] = (f32x4){0.f, 0.f, 0.f, 0.f};

  const int SH[8] = {0, 16, 4, 20, 8, 24, 12, 28};  // 4*AWQ_REVERSE_ORDER[j]
  unsigned int zz[8];  // packed fp16 (1024+z, 1024+z)
  unsigned int ss[8];  // packed fp16 (s, s)

  // ---------------- helpers as lambdas ----------------
  auto stageA = [&](int buf, int k0) {
    if (PRE) {
      #pragma unroll
      for (int i = 0; i < 4; ++i) {
        const int gb = i * 512 + wid * 64;   // wave-uniform granule base
        const int g  = gb + lane;
        const unsigned int r = (unsigned)(g >> 3), c = (unsigned)(g & 7);
        const unsigned short* gsrc =
            XH + (size_t)(row0 + r) * K_DIM + k0 + ((c ^ swz(r)) << 3);
        __builtin_amdgcn_global_load_lds(
            (const __attribute__((address_space(1))) void*)gsrc,
            (__attribute__((address_space(3))) void*)(&Alds[buf][gb * 8]),
            16, 0, 0);
      }
    } else {
      #pragma unroll
      for (int i = 0; i < 4; ++i) {
        const int g = i * 512 + tid;
        const unsigned int r = (unsigned)(g >> 3), c = (unsigned)(g & 7);
        const float* src = XF + (size_t)(row0 + r) * K_DIM + k0 + (c << 3);
        const float4 v0 = *(const float4*)src;
        const float4 v1 = *(const float4*)(src + 4);
        uint4 o;
        o.x = __builtin_bit_cast(unsigned int, __builtin_amdgcn_cvt_pkrtz(v0.x, v0.y));
        o.y = __builtin_bit_cast(unsigned int, __builtin_amdgcn_cvt_pkrtz(v0.z, v0.w));
        o.z = __builtin_bit_cast(unsigned int, __builtin_amdgcn_cvt_pkrtz(v1.x, v1.y));
        o.w = __builtin_bit_cast(unsigned int, __builtin_amdgcn_cvt_pkrtz(v1.z, v1.w));
        *(uint4*)((char*)&Alds[buf][0] + r * 128 + ((c ^ swz(r)) << 4)) = o;
      }
    }
  };

  auto prepGroup = [&](int grp) {
    const unsigned int qzv = (unsigned int)QZ[grp * NPACK + p0 + dq_p];
    const float* sp = S + (size_t)grp * N_DIM + n0 + dq_p * 8;
    const float4 sv0 = *(const float4*)sp;
    const float4 sv1 = *(const float4*)(sp + 4);
    const float svf[8] = {sv0.x, sv0.y, sv0.z, sv0.w, sv1.x, sv1.y, sv1.z, sv1.w};
    #pragma unroll
    for (int j = 0; j < 8; ++j) {
      const unsigned int z = (qzv >> SH[j]) & 15u;
      zz[j] = z * 0x10001u + 0x64006400u;
      ss[j] = __builtin_bit_cast(unsigned int, __builtin_amdgcn_cvt_pkrtz(svf[j], svf[j]));
    }
  };

  unsigned int qwc[4];   // qweight words for the tile being dequanted
  unsigned int qwn[4];   // prefetch for the tile after

  auto loadQW = [&](unsigned int* dst, int k0) {
    #pragma unroll
    for (int i = 0; i < 4; ++i)
      dst[i] = (unsigned int)QW[(size_t)(k0 + dq_k + i) * NPACK + p0 + dq_p];
  };

  auto dequantWriteB = [&](int buf, const unsigned int* qw) {
    #pragma unroll
    for (int j = 0; j < 8; ++j) {
      const int sh = SH[j];
      const unsigned int q01 =
          ((qw[0] >> sh) & 15u) | (((qw[1] >> sh) & 15u) << 16) | 0x64006400u;
      const unsigned int q23 =
          ((qw[2] >> sh) & 15u) | (((qw[3] >> sh) & 15u) << 16) | 0x64006400u;
      const h2 w01 = (__builtin_bit_cast(h2, q01) - __builtin_bit_cast(h2, zz[j])) *
                     __builtin_bit_cast(h2, ss[j]);
      const h2 w23 = (__builtin_bit_cast(h2, q23) - __builtin_bit_cast(h2, zz[j])) *
                     __builtin_bit_cast(h2, ss[j]);
      uint2 wb;
      wb.x = __builtin_bit_cast(unsigned int, w01);
      wb.y = __builtin_bit_cast(unsigned int, w23);
      const unsigned int nn = dq_p * 8 + j;
      *(uint2*)((char*)&Blds[buf][0] + nn * 128 + ((dq_k * 2) ^ (swz(nn) << 4))) = wb;
    }
  };

  // ---------------- prologue: fill buffer 0 ----------------
  stageA(0, 0);
  prepGroup(0);
  loadQW(qwc, 0);
  dequantWriteB(0, qwc);
  loadQW(qwn, BK);          // prefetch tile 1
  __syncthreads();          // buffer 0 ready

  int cur = 0;
  for (int t = 0; t < NT; ++t) {
    // ---- issue next tile's staging into buf[cur^1] (latency hides under MFMA) ----
    if (t + 1 < NT) {
      const int kn = (t + 1) * BK;
      stageA(cur ^ 1, kn);
      if (((t + 1) & 1) == 0) prepGroup((t + 1) >> 1);
      dequantWriteB(cur ^ 1, qwn);
      if (t + 2 < NT) loadQW(qwn, kn + BK);
    }

    // ---- MFMA on buf[cur]: 2 k-halves x 8x4 fragments ----
    const char* Ac = (const char*)&Alds[cur][0];
    const char* Bc = (const char*)&Blds[cur][0];
    #pragma unroll
    for (int kk = 0; kk < 2; ++kk) {
      f16x8 af[8], bfv[4];
      #pragma unroll
      for (int m = 0; m < 8; ++m) {
        const unsigned int r = (unsigned)(wr * 128 + m * 16 + l15);
        af[m] = *(const f16x8*)(Ac + r * 128 + (((unsigned)(kk * 4 + l4) ^ swz(r)) << 4));
      }
      #pragma unroll
      for (int n = 0; n < 4; ++n) {
        const unsigned int r = (unsigned)(wc * 64 + n * 16 + l15);
        bfv[n] = *(const f16x8*)(Bc + r * 128 + (((unsigned)(kk * 4 + l4) ^ swz(r)) << 4));
      }
      #pragma unroll
      for (int m = 0; m < 8; ++m)
        #pragma unroll
        for (int n = 0; n < 4; ++n)
          acc[m][n] = __builtin_amdgcn_mfma_f32_16x16x32_f16(af[m], bfv[n], acc[m][n], 0, 0, 0);
    }

    __syncthreads();   // drains this iter's glds/ds_writes; buf[cur^1] ready
    cur ^= 1;
  }

  // ---------------- epilogue: + bias, store fp32 ----------------
  // C/D layout (m89, dtype-independent): col = lane&15, row = (lane>>4)*4 + reg
  #pragma unroll
  for (int n = 0; n < 4; ++n) {
    const int col = n0 + wc * 64 + n * 16 + l15;
    const float bz = BIAS[col];
    #pragma unroll
    for (int m = 0; m < 8; ++m) {
      const int rbase = row0 + wr * 128 + m * 16 + l4 * 4;
      #pragma unroll
      for (int r = 0; r < 4; ++r) {
        OUT[(size_t)(rbase + r) * N_DIM + col] = acc[m][n][r] + bz;
      }
    }
  }
}

extern "C" void kernel_launch(void* const* d_in, const int* in_sizes, int n_in,
                              void* d_out, int out_size, void* d_ws, size_t ws_size,
                              hipStream_t stream) {
  const float* x = nullptr; const int* qw = nullptr; const int* qz = nullptr;
  const float* s = nullptr; const float* b = nullptr;
  for (int i = 0; i < n_in; ++i) {
    switch (in_sizes[i]) {
      case M_DIM * K_DIM:   x  = (const float*)d_in[i]; break;
      case K_DIM * NPACK:   qw = (const int*)d_in[i];   break;
      case NGROUPS * NPACK: qz = (const int*)d_in[i];   break;
      case NGROUPS * N_DIM: s  = (const float*)d_in[i]; break;
      case N_DIM:           b  = (const float*)d_in[i]; break;
    }
  }
  float* out = (float*)d_out;

  dim3 grid(N_DIM / BN, M_DIM / BM);  // 43 x 4 = 172 blocks
  const size_t xh_bytes = (size_t)M_DIM * K_DIM * 2;
  if (ws_size >= xh_bytes) {
    unsigned short* xh = (unsigned short*)d_ws;
    conv_x<<<(M_DIM * K_DIM) / (256 * 8), 256, 0, stream>>>(x, xh);
    awq_gemm<true><<<grid, dim3(512), 0, stream>>>(xh, nullptr, qw, qz, s, b, out);
  } else {
    awq_gemm<false><<<grid, dim3(512), 0, stream>>>(nullptr, x, qw, qz, s, b, out);
  }
}